// Round 1
// 32.721 us; speedup vs baseline: 1.0403x; 1.0403x over previous
//
#include <hip/hip_runtime.h>
#include <hip/hip_bf16.h>

// MCorrLCorr via bf16 MFMA GEMM, per (b,hx) block:
//   out[b,o,hx,hy] = sum_{c,fx,fy} in[b,c,(hx+1)(fx+1)-1, 2hy+fy-2] * w[o,c,fx,fy] + bias[o]
// GEMM: C[o,hy] = A[o,k]*B[k,hy], k = c*32+fx*8+fy (K=1024).
// 8 waves = 2 o-halves x 4 hy-quarters (32o x 48hy per wave, mt2/tt3), full K per wave
// (no K-split -> no epilogue LDS reduction).
// A: per-wave fragments loaded DIRECTLY from L2/L1-resident prepped wl[] into registers
//    (no LDS, no global_load_lds) -> barrier needs NO vmcnt drain.
// B: staged X rows in LDS (stride 200 dwords -> uniform 2-way bank access = free),
//    double-buffered, X global loads prefetched 2 iterations deep; per-iter sync is
//    raw s_barrier + lgkmcnt(0) only, so HBM loads stay in flight across barriers.

#define Bb   16
#define NGX  128
#define NGY  384
#define Oo   64
#define NHX  32
#define NHY  190

#define HEAD 4                   // head pad shorts (8B-aligned data start)
#define RSX  400                 // X row stride in shorts = 200 dwords (4 head + 384 + 12 pad)
#define XBUF (16 * RSX)          // shorts per X buffer (16 rows/iter)

typedef short bf16x8 __attribute__((ext_vector_type(8)));
typedef float f32x4  __attribute__((ext_vector_type(4)));
typedef unsigned short u16x4 __attribute__((ext_vector_type(4)));

__device__ __forceinline__ unsigned short f2bf(float f) {
  __hip_bfloat16 h = __float2bfloat16(f);
  return __builtin_bit_cast(unsigned short, h);
}

// wl[(k>>3)*512 + o*8 + (k&7)] = bf16(w[o*1024 + k])
// -> a wave's 16B A-frag (o = base+lo16, k8 = ks*4+gq) is 16 consecutive 16B chunks
//    per gq group: fully coalesced dwordx4 loads, L1/L2-hot (128 KB total).
__global__ void wprep_kernel(const float* __restrict__ w, unsigned short* __restrict__ wl) {
  int idx = blockIdx.x * 256 + threadIdx.x;
  if (idx >= Oo * 1024) return;
  int k8 = idx >> 9;             // k/8: 0..127
  int o  = (idx >> 3) & 63;
  int j  = idx & 7;
  wl[idx] = f2bf(w[o * 1024 + k8 * 8 + j]);
}

__global__ __launch_bounds__(512, 4)
void mcorr_mfma_kernel(const float* __restrict__ in, const unsigned short* __restrict__ wl,
                       const float* __restrict__ bias, float* __restrict__ out) {
  const int tid  = threadIdx.x;
  const int l    = tid & 63;
  const int wv   = tid >> 6;          // 8 waves
  const int wo   = wv >> 2;           // o half: o in [32*wo, 32*wo+32)
  const int whq  = wv & 3;            // hy quarter: hy in [48*whq, 48*whq+48)
  const int lo16 = l & 15, gq = l >> 4;

  // XCD swizzle: XCD x gets 2 consecutive b's worth of blocks (all hx -> L2 row reuse)
  int lid = blockIdx.x + NHX * blockIdx.y;
  int swz = (lid & 7) * 64 + (lid >> 3);
  const int hx = swz & 31;
  const int b  = swz >> 5;

  __shared__ __align__(16) unsigned short xs_[2 * XBUF];   // 25.6 KB

  f32x4 acc[2][3];
  #pragma unroll
  for (int i = 0; i < 2; ++i)
    #pragma unroll
    for (int j = 0; j < 3; ++j) acc[i][j] = (f32x4){0.f, 0.f, 0.f, 0.f};

  // zero pad regions once: shorts [0,HEAD) and [384+HEAD-... tail] per row per buffer
  {
    int bu = tid >> 8, row = (tid >> 4) & 15, j = tid & 15;
    xs_[bu * XBUF + row * RSX + (j < HEAD ? j : 384 + j)] = 0;
  }

  // X staging: 32 threads per row r_st = c_local*4 + fx (16 rows per iter)
  const int r_st  = tid >> 5;
  const int j0    = tid & 31;
  const int fx_st = r_st & 3;
  const int c_st  = r_st >> 2;                             // channel = 4t + c_st
  const int gx_st = (hx + 1) * (fx_st + 1) - 1;            // always in [0, NGX)
  const float* xbase = in + (((size_t)b * 32 + c_st) * NGX + gx_st) * NGY;
  const size_t cstep = (size_t)4 * NGX * NGY;              // +4 c per iter

  float4 xv[2][3];                                         // 2-deep prefetch sets

#define XLOAD(T) do {                                                    \
    const float* xb_ = xbase + (size_t)(T) * cstep;                      \
    _Pragma("unroll") for (int s_ = 0; s_ < 3; ++s_)                     \
      xv[(T) & 1][s_] = *(const float4*)(xb_ + 4 * j0 + 128 * s_);       \
  } while (0)

#define XCOMMIT(T) do {                                                  \
    unsigned short* row_ = xs_ + ((T) & 1) * XBUF + r_st * RSX;          \
    _Pragma("unroll") for (int s_ = 0; s_ < 3; ++s_) {                   \
      u16x4 h_;                                                          \
      h_[0] = f2bf(xv[(T) & 1][s_].x); h_[1] = f2bf(xv[(T) & 1][s_].y);  \
      h_[2] = f2bf(xv[(T) & 1][s_].z); h_[3] = f2bf(xv[(T) & 1][s_].w);  \
      *(u16x4*)&row_[HEAD + 4 * j0 + 128 * s_] = h_;                     \
    }                                                                    \
  } while (0)

  // raw barrier: drain LDS writes only; global loads stay in flight across it
#define BAR() do {                                                       \
    asm volatile("s_waitcnt lgkmcnt(0)" ::: "memory");                   \
    __builtin_amdgcn_s_barrier();                                        \
  } while (0)

#define COMPUTE(T) do {                                                              \
    const unsigned* Xb_ = (const unsigned*)(xs_ + ((T) & 1) * XBUF);                 \
    _Pragma("unroll") for (int cs_ = 0; cs_ < 4; ++cs_) {                            \
      const unsigned short* ap_ =                                                    \
          wl + ((4 * (T) + cs_) * 4 + gq) * 512 + (32 * wo + lo16) * 8;              \
      bf16x8 a0_ = *(const bf16x8*)ap_;                                              \
      bf16x8 a1_ = *(const bf16x8*)(ap_ + 128);   /* +16 o */                        \
      const int r_ = cs_ * 4 + gq;                                                   \
      _Pragma("unroll") for (int tt_ = 0; tt_ < 3; ++tt_) {                          \
        int hy_ = 48 * whq + 16 * tt_ + lo16;                                        \
        const unsigned* xp_ = &Xb_[r_ * 200 + 1 + hy_];                              \
        union { unsigned u[4]; bf16x8 v; } bb_;                                      \
        bb_.u[0] = xp_[0]; bb_.u[1] = xp_[1];                                        \
        bb_.u[2] = xp_[2]; bb_.u[3] = xp_[3];                                        \
        acc[0][tt_] = __builtin_amdgcn_mfma_f32_16x16x32_bf16(                       \
            a0_, bb_.v, acc[0][tt_], 0, 0, 0);                                       \
        acc[1][tt_] = __builtin_amdgcn_mfma_f32_16x16x32_bf16(                       \
            a1_, bb_.v, acc[1][tt_], 0, 0, 0);                                       \
      }                                                                              \
    }                                                                                \
  } while (0)

  // ---- prologue: fill prefetch pipe, stage iteration 0 ----
  XLOAD(0);
  XLOAD(1);
  XCOMMIT(0);      // waits only set-0 loads (compiler counted vmcnt)
  BAR();

  // ---- main loop: 8 iterations, one lgkm-only barrier each ----
  #pragma unroll
  for (int t = 0; t < 8; ++t) {
    if (t < 6) XLOAD(t + 2);             // issue 2 iters ahead, flies across barriers
    COMPUTE(t);                          // ds_reads + reg A-loads + MFMA
    if (t < 7) { XCOMMIT(t + 1); BAR(); }
  }

  // ---- epilogue: bias + store (no cross-wave reduction needed) ----
  #pragma unroll
  for (int mt = 0; mt < 2; ++mt) {
    #pragma unroll
    for (int reg = 0; reg < 4; ++reg) {
      int o = 32 * wo + 16 * mt + 4 * gq + reg;
      float bv = bias[o];
      #pragma unroll
      for (int tt = 0; tt < 3; ++tt) {
        int hy = 48 * whq + 16 * tt + lo16;
        if (hy < NHY)
          out[(((size_t)b * Oo + o) * NHX + hx) * NHY + hy] = acc[mt][tt][reg] + bv;
      }
    }
  }
}

extern "C" void kernel_launch(void* const* d_in, const int* in_sizes, int n_in,
                              void* d_out, int out_size, void* d_ws, size_t ws_size,
                              hipStream_t stream) {
  const float* in   = (const float*)d_in[0];
  const float* w    = (const float*)d_in[1];
  const float* bias = (const float*)d_in[2];
  float* out = (float*)d_out;
  unsigned short* wl = (unsigned short*)d_ws;   // 128 KB scratch

  wprep_kernel<<<(Oo * 1024 + 255) / 256, 256, 0, stream>>>(w, wl);

  dim3 grid(NHX, Bb);
  mcorr_mfma_kernel<<<grid, 512, 0, stream>>>(in, wl, bias, out);
}